// Round 1
// baseline (375.399 us; speedup 1.0000x reference)
//
#include <hip/hip_runtime.h>
#include <math.h>

// LSEP loss: loss = log1p( sum_rows (sum_{t==0} exp(x)) * (sum_{t>0} exp(-x)) ) / B
// Memory-bound streaming reduction: 384 MB read, scalar out.

constexpr int ROWS = 2000000;
constexpr int COLS = 24;           // 6 x float4 per row, 96 B
constexpr int BLOCK = 256;
constexpr int GRID = 2048;         // grid-stride; ~3.8 rows/thread

__global__ void lsep_zero_ws(double* ws) {
    ws[0] = 0.0;
}

__global__ __launch_bounds__(BLOCK) void lsep_main(
        const float* __restrict__ input,
        const int*   __restrict__ target,
        double*      __restrict__ ws) {
    const int tid    = blockIdx.x * blockDim.x + threadIdx.x;
    const int stride = gridDim.x * blockDim.x;

    double acc = 0.0;

    for (int row = tid; row < ROWS; row += stride) {
        const float4* __restrict__ fin = reinterpret_cast<const float4*>(input + (size_t)row * COLS);
        const int4*   __restrict__ tin = reinterpret_cast<const int4*>(target + (size_t)row * COLS);

        float s_neg = 0.0f;   // sum exp(x) over t==0
        float s_pos = 0.0f;   // sum exp(-x) over t>0

        #pragma unroll
        for (int j = 0; j < 6; ++j) {
            const float4 x = fin[j];
            const int4   t = tin[j];
            float e;
            e = __expf(t.x > 0 ? -x.x : x.x); if (t.x > 0) s_pos += e; else s_neg += e;
            e = __expf(t.y > 0 ? -x.y : x.y); if (t.y > 0) s_pos += e; else s_neg += e;
            e = __expf(t.z > 0 ? -x.z : x.z); if (t.z > 0) s_pos += e; else s_neg += e;
            e = __expf(t.w > 0 ? -x.w : x.w); if (t.w > 0) s_pos += e; else s_neg += e;
        }
        acc += (double)s_neg * (double)s_pos;
    }

    // Wave (64-lane) shuffle reduction
    #pragma unroll
    for (int off = 32; off > 0; off >>= 1)
        acc += __shfl_down(acc, off, 64);

    __shared__ double sdata[BLOCK / 64];
    const int lane = threadIdx.x & 63;
    const int wave = threadIdx.x >> 6;
    if (lane == 0) sdata[wave] = acc;
    __syncthreads();

    if (threadIdx.x == 0) {
        double s = 0.0;
        #pragma unroll
        for (int w = 0; w < BLOCK / 64; ++w) s += sdata[w];
        atomicAdd(ws, s);   // device-scope f64 atomic (global_atomic_add_f64)
    }
}

__global__ void lsep_finalize(const double* __restrict__ ws, float* __restrict__ out) {
    out[0] = (float)(log1p(ws[0]) / (double)ROWS);
}

extern "C" void kernel_launch(void* const* d_in, const int* in_sizes, int n_in,
                              void* d_out, int out_size, void* d_ws, size_t ws_size,
                              hipStream_t stream) {
    const float* input  = (const float*)d_in[0];
    const int*   target = (const int*)d_in[1];
    float*       out    = (float*)d_out;
    double*      ws     = (double*)d_ws;   // ws[0] = running total (re-poisoned each call)

    lsep_zero_ws<<<1, 1, 0, stream>>>(ws);
    lsep_main<<<GRID, BLOCK, 0, stream>>>(input, target, ws);
    lsep_finalize<<<1, 1, 0, stream>>>(ws, out);
}